// Round 2
// baseline (195.861 us; speedup 1.0000x reference)
//
#include <hip/hip_runtime.h>

// out[b,n,m] = cost_class + cost_mask + cost_dice
//   dot[b,n,m] = sum_l sigmoid(p[b,n,l]) * t[b,m,l]   (bf16 MFMA, fp32 acc)
//   sum_p[b,n] = sum_l sigmoid(p)  (fp32, exact path)
//   sum_t[b,m] = sum_l t           (fp32, exact path)
//   cost_class = -logits[b,n,label[b,m]]
//   cost_mask  = -(2*dot + L - sum_p - sum_t)/L
//   cost_dice  = 1 - (2*dot + 1)/(sum_p + sum_t + 1)
//
// R2: CS 128->256 (1KB contiguous per row per block, NCH=1) to fix DRAM
// read granularity; one wave-load = one 1KB burst; no guards (100=4x25, 20=4x5).

#define Lsz 65536
#define Bb 4
#define Nn 100
#define Mm 20
#define Cc 81
#define CS 256                  // l-chunk per staging pass (1KB contiguous per row)
#define NP 112                  // padded N stride in ws dot region
#define Pp (20 * NP + NP + 32)  // 2240 dot + 112 sum_p + 32 sum_t(padded) = 2384
#define KSTR 264                // LDS row stride in ushorts (256 bf16 + 8 pad; 528B = 33*16)
#define TPO 16                  // lanes cooperating per output in hung_fin

typedef short bf16x8 __attribute__((ext_vector_type(8)));
typedef float fx4 __attribute__((ext_vector_type(4)));

__device__ __forceinline__ float sigmoid_fast(float x) {
    float e = __builtin_amdgcn_exp2f(x * -1.44269504088896340736f);
    return __builtin_amdgcn_rcpf(1.0f + e);
}

__device__ __forceinline__ ushort bf16rne(float f) {
    union { float f; unsigned u; } v; v.f = f;
    unsigned u = v.u;
    u += 0x7fffu + ((u >> 16) & 1u);
    return (ushort)(u >> 16);
}

// LDS 74.3KB -> 2 blocks/CU (8 waves/CU, proven sufficient in R0/R1).
__global__ __launch_bounds__(256) void hung_main(
    const float* __restrict__ pm,   // (B,N,L)
    const float* __restrict__ gm,   // (B,M,L)
    float* __restrict__ ws,         // (B,KBW,Pp)
    int KBW, int NCH)
{
    __shared__ __align__(16) ushort ldsA[NP * KSTR];  // sigma(p) bf16, [n][k]
    __shared__ __align__(16) ushort ldsB[32 * KSTR];  // t bf16, [m][k]

    const int tid  = threadIdx.x;
    const int slot = blockIdx.x;
    const int b    = blockIdx.y;
    const int q    = tid & 63;        // float4-quad within 256-float row chunk
    const int w    = tid >> 6;        // wave 0..3 == row phase
    const int lane = tid & 63;
    const int lr   = lane & 15;
    const int kg   = lane >> 4;       // 0..3

    float sp[25], st[5];
    #pragma unroll
    for (int p = 0; p < 25; ++p) sp[p] = 0.f;
    #pragma unroll
    for (int p = 0; p < 5; ++p) st[p] = 0.f;

    fx4 acc00 = {0.f, 0.f, 0.f, 0.f};
    fx4 acc01 = {0.f, 0.f, 0.f, 0.f};
    fx4 acc10 = {0.f, 0.f, 0.f, 0.f};
    fx4 acc11 = {0.f, 0.f, 0.f, 0.f};

    const float* pbase = pm + (size_t)b * Nn * Lsz + 4 * q;
    const float* tbase = gm + (size_t)b * Mm * Lsz + 4 * q;

    for (int c = 0; c < NCH; ++c) {
        const int l0 = (slot * NCH + c) * CS;
        if (c) __syncthreads();  // prev chunk's LDS reads done before overwrite

        // ---- stage A: sigma(pred_masks) -> bf16 LDS [n][k]
        // wave w loads rows {w, w+4, ...}: each wave-load = 1KB contiguous burst
        #pragma unroll
        for (int p = 0; p < 25; ++p) {
            const int r = w + 4 * p;                  // 100 = 4*25, no guard
            float4 v = *(const float4*)(pbase + (size_t)r * Lsz + l0);
            float s0 = sigmoid_fast(v.x), s1 = sigmoid_fast(v.y);
            float s2 = sigmoid_fast(v.z), s3 = sigmoid_fast(v.w);
            sp[p] += (s0 + s1) + (s2 + s3);
            ushort4 o = { bf16rne(s0), bf16rne(s1), bf16rne(s2), bf16rne(s3) };
            *(ushort4*)&ldsA[r * KSTR + 4 * q] = o;
        }
        // ---- stage B: gt_masks -> bf16 LDS [m][k]
        #pragma unroll
        for (int p = 0; p < 5; ++p) {
            const int r = w + 4 * p;                  // 20 = 4*5, no guard
            float4 v = *(const float4*)(tbase + (size_t)r * Lsz + l0);
            st[p] += (v.x + v.y) + (v.z + v.w);
            ushort4 o = { bf16rne(v.x), bf16rne(v.y), bf16rne(v.z), bf16rne(v.w) };
            *(ushort4*)&ldsB[r * KSTR + 4 * q] = o;
        }
        __syncthreads();

        // ---- MFMA: wave w owns n-tiles {2w, 2w+1}, m-tiles {0,1}
        #pragma unroll
        for (int kk = 0; kk < 8; ++kk) {
            const int ko = kk * 32 + kg * 8;  // ushort offset within row
            bf16x8 a0 = *(const bf16x8*)&ldsA[(32 * w + lr) * KSTR + ko];
            bf16x8 b0 = *(const bf16x8*)&ldsB[lr * KSTR + ko];
            bf16x8 b1 = *(const bf16x8*)&ldsB[(16 + lr) * KSTR + ko];
            acc00 = __builtin_amdgcn_mfma_f32_16x16x32_bf16(a0, b0, acc00, 0, 0, 0);
            acc01 = __builtin_amdgcn_mfma_f32_16x16x32_bf16(a0, b1, acc01, 0, 0, 0);
            if (w < 3) {  // n-tile 7 (rows 112..127) doesn't exist
                bf16x8 a1 = *(const bf16x8*)&ldsA[(32 * w + 16 + lr) * KSTR + ko];
                acc10 = __builtin_amdgcn_mfma_f32_16x16x32_bf16(a1, b0, acc10, 0, 0, 0);
                acc11 = __builtin_amdgcn_mfma_f32_16x16x32_bf16(a1, b1, acc11, 0, 0, 0);
            }
        }
    }

    // ---- reduce sum_p / sum_t across the 64 q-lanes of each wave
    #pragma unroll
    for (int p = 0; p < 25; ++p)
        #pragma unroll
        for (int o = 32; o > 0; o >>= 1) sp[p] += __shfl_xor(sp[p], o);
    #pragma unroll
    for (int p = 0; p < 5; ++p)
        #pragma unroll
        for (int o = 32; o > 0; o >>= 1) st[p] += __shfl_xor(st[p], o);

    float* wsb = ws + (size_t)(b * KBW + slot) * Pp;
    if (lane == 0) {
        #pragma unroll
        for (int p = 0; p < 25; ++p) wsb[20 * NP + (w + 4 * p)] = sp[p];
        #pragma unroll
        for (int p = 0; p < 5; ++p)  wsb[20 * NP + NP + (w + 4 * p)] = st[p];
    }

    // ---- store dot partials: D col = lane&15 (m), row = kg*4 + reg (n-local)
    const int nb = 32 * w + kg * 4;
    #pragma unroll
    for (int e = 0; e < 4; ++e) {
        const int n0 = nb + e;
        if (n0 < Nn) {
            wsb[lr * NP + n0] = acc00[e];
            if (lr < 4) wsb[(16 + lr) * NP + n0] = acc01[e];
        }
        const int n1 = nb + 16 + e;
        if (w < 3 && n1 < Nn) {
            wsb[lr * NP + n1] = acc10[e];
            if (lr < 4) wsb[(16 + lr) * NP + n1] = acc11[e];
        }
    }
}

// TPO=16 lanes team per output: 500 blocks, 16-deep reduction with unroll 8
// -> ~2 dependent memory rounds; shuffle tree combines the 16 parts.
__global__ __launch_bounds__(256) void hung_fin(
    const float* __restrict__ ws,
    const float* __restrict__ logits,   // (B,N,C)
    const int*   __restrict__ labels,   // (B,M)
    float* __restrict__ out,            // (B,N,M)
    int KBW)
{
    const int gt   = blockIdx.x * 256 + threadIdx.x;
    const int oi   = gt / TPO;
    const int part = gt & (TPO - 1);
    if (oi >= Bb * Nn * Mm) return;
    const int b = oi / (Nn * Mm);
    const int r = oi % (Nn * Mm);
    const int m = r / Nn;       // n fast-varying -> coalesced-ish ws reads
    const int n = r % Nn;

    const float* p = ws + (size_t)(b * KBW + part) * Pp;
    const size_t step = (size_t)TPO * Pp;
    float dot = 0.f, sp = 0.f, st = 0.f;
    const int iters = KBW / TPO;
    #pragma unroll 8
    for (int j = 0; j < iters; ++j) {
        dot += p[m * NP + n];
        sp  += p[20 * NP + n];
        st  += p[20 * NP + NP + m];
        p += step;
    }

    #pragma unroll
    for (int o = TPO >> 1; o > 0; o >>= 1) {
        dot += __shfl_xor(dot, o);
        sp  += __shfl_xor(sp, o);
        st  += __shfl_xor(st, o);
    }

    if (part == 0) {
        int lab = labels[b * Mm + m];
        float cc = -logits[(size_t)(b * Nn + n) * Cc + lab];
        const float invL = 1.0f / (float)Lsz;
        float cm = -(2.f * dot + (float)Lsz - sp - st) * invL;
        float cd = 1.f - (2.f * dot + 1.f) / (sp + st + 1.f);
        out[(size_t)b * (Nn * Mm) + n * Mm + m] = cc + cm + cd;
    }
}

extern "C" void kernel_launch(void* const* d_in, const int* in_sizes, int n_in,
                              void* d_out, int out_size, void* d_ws, size_t ws_size,
                              hipStream_t stream) {
    const float* logits = (const float*)d_in[0];
    const float* pmasks = (const float*)d_in[1];
    const int*   labels = (const int*)d_in[2];
    const float* gmasks = (const float*)d_in[3];
    float* out = (float*)d_out;
    float* ws  = (float*)d_ws;

    int KBW = 256;  // split-K slots per batch; 9.77 MB of ws at 256
    while (KBW > 1 && (size_t)Bb * KBW * Pp * sizeof(float) > ws_size) KBW >>= 1;
    int NCH = (Lsz / CS) / KBW;  // chunks per block (1 at KBW=256)

    hung_main<<<dim3(KBW, Bb), 256, 0, stream>>>(pmasks, gmasks, ws, KBW, NCH);
    hung_fin<<<(Bb * Nn * Mm * TPO + 255) / 256, 256, 0, stream>>>(ws, logits, labels, out, KBW);
}

// Round 4
// 176.899 us; speedup vs baseline: 1.1072x; 1.1072x over previous
//
#include <hip/hip_runtime.h>

// out[b,n,m] = cost_class + cost_mask + cost_dice
//   dot[b,n,m] = sum_l sigmoid(p[b,n,l]) * t[b,m,l]   (bf16 MFMA, fp32 acc)
//   sum_p[b,n] = sum_l sigmoid(p)  (fp32, exact path)
//   sum_t[b,m] = sum_l t           (fp32, exact path)
//   cost_class = -logits[b,n,label[b,m]]
//   cost_mask  = -(2*dot + L - sum_p - sum_t)/L
//   cost_dice  = 1 - (2*dot + 1)/(sum_p + sum_t + 1)
//
// R4 = R3 with the nontemporal load done via a clang ext_vector float4
// (the builtin rejects HIP_vector_type). Theory unchanged: the 400MiB ws
// poison fill leaves the 256MiB LLC full of dirty lines; normal streaming
// reads evict them -> ~126MB forced writebacks during main (invariant
// ~60us). nt loads don't allocate -> no drain.

#define Lsz 65536
#define Bb 4
#define Nn 100
#define Mm 20
#define Cc 81
#define CS 128                  // l-chunk per staging pass
#define NP 112                  // padded N stride in ws dot region
#define Pp (20 * NP + NP + 32)  // 2240 dot + 112 sum_p + 32 sum_t(padded) = 2384
#define KSTR 136                // LDS row stride in ushorts (128 bf16 + 8 pad; 272B = 17*16)
#define TPO 8                   // lanes cooperating per output in hung_fin

typedef short bf16x8 __attribute__((ext_vector_type(8)));
typedef float fx4 __attribute__((ext_vector_type(4)));
typedef float vf4 __attribute__((ext_vector_type(4)));  // native vec for nt loads

__device__ __forceinline__ float sigmoid_fast(float x) {
    float e = __builtin_amdgcn_exp2f(x * -1.44269504088896340736f);
    return __builtin_amdgcn_rcpf(1.0f + e);
}

__device__ __forceinline__ ushort bf16rne(float f) {
    union { float f; unsigned u; } v; v.f = f;
    unsigned u = v.u;
    u += 0x7fffu + ((u >> 16) & 1u);
    return (ushort)(u >> 16);
}

// 4 blocks/CU (LDS: 4 x 39.2KB = 157KB <= 160KB).
__global__ __launch_bounds__(256, 4) void hung_main(
    const float* __restrict__ pm,   // (B,N,L)
    const float* __restrict__ gm,   // (B,M,L)
    float* __restrict__ ws,         // (B,KBW,Pp)
    int KBW, int NCH)
{
    __shared__ __align__(16) ushort ldsA[NP * KSTR];  // sigma(p) bf16, [n][k]
    __shared__ __align__(16) ushort ldsB[32 * KSTR];  // t bf16, [m][k]

    const int tid  = threadIdx.x;
    const int slot = blockIdx.x;
    const int b    = blockIdx.y;
    const int q    = tid & 31;        // float4-quad within 128-float row chunk
    const int rr   = tid >> 5;        // 0..7, row phase
    const int lane = tid & 63;
    const int w    = tid >> 6;        // wave 0..3
    const int lr   = lane & 15;
    const int kg   = lane >> 4;       // 0..3

    float sp[13], st[3];
    #pragma unroll
    for (int p = 0; p < 13; ++p) sp[p] = 0.f;
    #pragma unroll
    for (int p = 0; p < 3; ++p) st[p] = 0.f;

    fx4 acc00 = {0.f, 0.f, 0.f, 0.f};
    fx4 acc01 = {0.f, 0.f, 0.f, 0.f};
    fx4 acc10 = {0.f, 0.f, 0.f, 0.f};
    fx4 acc11 = {0.f, 0.f, 0.f, 0.f};

    const float* pbase = pm + (size_t)b * Nn * Lsz + 4 * q;
    const float* tbase = gm + (size_t)b * Mm * Lsz + 4 * q;

    for (int c = 0; c < NCH; ++c) {
        const int l0 = (slot * NCH + c) * CS;
        __syncthreads();  // prev chunk's LDS reads done before overwrite

        // ---- stage A: sigma(pred_masks) -> bf16 LDS [n][k]  (nt: read-once)
        #pragma unroll
        for (int p = 0; p < 13; ++p) {
            const int r = rr + 8 * p;
            if (r < Nn) {
                vf4 v = __builtin_nontemporal_load(
                    (const vf4*)(pbase + (size_t)r * Lsz + l0));
                float s0 = sigmoid_fast(v.x), s1 = sigmoid_fast(v.y);
                float s2 = sigmoid_fast(v.z), s3 = sigmoid_fast(v.w);
                sp[p] += (s0 + s1) + (s2 + s3);
                ushort4 o = { bf16rne(s0), bf16rne(s1), bf16rne(s2), bf16rne(s3) };
                *(ushort4*)&ldsA[r * KSTR + 4 * q] = o;
            }
        }
        // ---- stage B: gt_masks -> bf16 LDS [m][k]  (nt: read-once)
        #pragma unroll
        for (int p = 0; p < 3; ++p) {
            const int r = rr + 8 * p;
            if (r < Mm) {
                vf4 v = __builtin_nontemporal_load(
                    (const vf4*)(tbase + (size_t)r * Lsz + l0));
                st[p] += (v.x + v.y) + (v.z + v.w);
                ushort4 o = { bf16rne(v.x), bf16rne(v.y), bf16rne(v.z), bf16rne(v.w) };
                *(ushort4*)&ldsB[r * KSTR + 4 * q] = o;
            }
        }
        __syncthreads();

        // ---- MFMA: wave w owns n-tiles {2w, 2w+1}, m-tiles {0,1}
        #pragma unroll
        for (int kk = 0; kk < 4; ++kk) {
            const int ko = kk * 32 + kg * 8;  // ushort offset within row
            bf16x8 a0 = *(const bf16x8*)&ldsA[(32 * w + lr) * KSTR + ko];
            bf16x8 b0 = *(const bf16x8*)&ldsB[lr * KSTR + ko];
            bf16x8 b1 = *(const bf16x8*)&ldsB[(16 + lr) * KSTR + ko];
            acc00 = __builtin_amdgcn_mfma_f32_16x16x32_bf16(a0, b0, acc00, 0, 0, 0);
            acc01 = __builtin_amdgcn_mfma_f32_16x16x32_bf16(a0, b1, acc01, 0, 0, 0);
            if (w < 3) {  // n-tile 7 (rows 112..127) doesn't exist
                bf16x8 a1 = *(const bf16x8*)&ldsA[(32 * w + 16 + lr) * KSTR + ko];
                acc10 = __builtin_amdgcn_mfma_f32_16x16x32_bf16(a1, b0, acc10, 0, 0, 0);
                acc11 = __builtin_amdgcn_mfma_f32_16x16x32_bf16(a1, b1, acc11, 0, 0, 0);
            }
        }
    }

    // ---- reduce sum_p / sum_t across the 32 q-lanes of each row group
    #pragma unroll
    for (int p = 0; p < 13; ++p)
        #pragma unroll
        for (int o = 16; o > 0; o >>= 1) sp[p] += __shfl_xor(sp[p], o, 32);
    #pragma unroll
    for (int p = 0; p < 3; ++p)
        #pragma unroll
        for (int o = 16; o > 0; o >>= 1) st[p] += __shfl_xor(st[p], o, 32);

    float* wsb = ws + (size_t)(b * KBW + slot) * Pp;
    if ((tid & 31) == 0) {
        #pragma unroll
        for (int p = 0; p < 13; ++p) {
            const int r = rr + 8 * p;
            if (r < Nn) wsb[20 * NP + r] = sp[p];
        }
        #pragma unroll
        for (int p = 0; p < 3; ++p) {
            const int r = rr + 8 * p;
            if (r < Mm) wsb[20 * NP + NP + r] = st[p];
        }
    }

    // ---- store dot partials: D col = lane&15 (m), row = kg*4 + reg (n-local)
    const int nb = 32 * w + kg * 4;
    #pragma unroll
    for (int e = 0; e < 4; ++e) {
        const int n0 = nb + e;
        if (n0 < Nn) {
            wsb[lr * NP + n0] = acc00[e];
            if (lr < 4) wsb[(16 + lr) * NP + n0] = acc01[e];
        }
        const int n1 = nb + 16 + e;
        if (w < 3 && n1 < Nn) {
            wsb[lr * NP + n1] = acc10[e];
            if (lr < 4) wsb[(16 + lr) * NP + n1] = acc11[e];
        }
    }
}

// TPO=8 lanes team up per output: 250 blocks, KBW/TPO-deep loop with
// unroll 8 -> 24 loads in flight, ~4 dependent rounds.
__global__ __launch_bounds__(256) void hung_fin(
    const float* __restrict__ ws,
    const float* __restrict__ logits,   // (B,N,C)
    const int*   __restrict__ labels,   // (B,M)
    float* __restrict__ out,            // (B,N,M)
    int KBW)
{
    const int gt   = blockIdx.x * 256 + threadIdx.x;
    const int oi   = gt / TPO;
    const int part = gt & (TPO - 1);
    if (oi >= Bb * Nn * Mm) return;
    const int b = oi / (Nn * Mm);
    const int r = oi % (Nn * Mm);
    const int m = r / Nn;       // n fast-varying -> coalesced-ish ws reads
    const int n = r % Nn;

    const float* p = ws + (size_t)(b * KBW + part) * Pp;
    const size_t step = (size_t)TPO * Pp;
    float dot = 0.f, sp = 0.f, st = 0.f;
    const int iters = KBW / TPO;
    #pragma unroll 8
    for (int j = 0; j < iters; ++j) {
        dot += p[m * NP + n];
        sp  += p[20 * NP + n];
        st  += p[20 * NP + NP + m];
        p += step;
    }

    #pragma unroll
    for (int o = TPO >> 1; o > 0; o >>= 1) {
        dot += __shfl_xor(dot, o);
        sp  += __shfl_xor(sp, o);
        st  += __shfl_xor(st, o);
    }

    if (part == 0) {
        int lab = labels[b * Mm + m];
        float cc = -logits[(size_t)(b * Nn + n) * Cc + lab];
        const float invL = 1.0f / (float)Lsz;
        float cm = -(2.f * dot + (float)Lsz - sp - st) * invL;
        float cd = 1.f - (2.f * dot + 1.f) / (sp + st + 1.f);
        out[(size_t)b * (Nn * Mm) + n * Mm + m] = cc + cm + cd;
    }
}

extern "C" void kernel_launch(void* const* d_in, const int* in_sizes, int n_in,
                              void* d_out, int out_size, void* d_ws, size_t ws_size,
                              hipStream_t stream) {
    const float* logits = (const float*)d_in[0];
    const float* pmasks = (const float*)d_in[1];
    const int*   labels = (const int*)d_in[2];
    const float* gmasks = (const float*)d_in[3];
    float* out = (float*)d_out;
    float* ws  = (float*)d_ws;

    int KBW = 256;  // split-K slots per batch: grid 1024 = 4 blocks/CU
    while (KBW > 1 && (size_t)Bb * KBW * Pp * sizeof(float) > ws_size) KBW >>= 1;
    int NCH = (Lsz / CS) / KBW;  // chunks per block (2 at KBW=256)

    hung_main<<<dim3(KBW, Bb), 256, 0, stream>>>(pmasks, gmasks, ws, KBW, NCH);
    hung_fin<<<(Bb * Nn * Mm * TPO + 255) / 256, 256, 0, stream>>>(ws, logits, labels, out, KBW);
}